// Round 22
// baseline (26.810 us; speedup 1.0000x reference)
//
#include <hip/hip_runtime.h>
#include <math.h>

#define B_N 4096
#define C_N 100
#define CPAD 112
#define D_N 384
#define EPSF 1e-12f
#define NTILES 7          // class tiles of 16 (112 padded)
#define NKT24 24          // K=768 -> 24 ktiles of 32
#define NRT2 132          // 128 input 32-row tiles + 4 center 32-row tiles
#define NGRP 264          // 256 input row-groups of 16 + 8 center groups

typedef __attribute__((ext_vector_type(8))) short short8;
typedef __attribute__((ext_vector_type(4))) float f32x4;

static __device__ __forceinline__ short f2bf(float f) {
    unsigned u = __float_as_uint(f);
    u = (u + 0x7FFFu + ((u >> 16) & 1u)) >> 16;
    return (short)u;
}

// Fragment layouts (HW-verified r20): lane l, elem e of a 16x16x32 frag holds
//   A[row = l&15][k = (l>>4)*8 + e]   /   B[k = (l>>4)*8 + e][col = l&15]
// A matrix [4224 rows][K=768]: k<384 -> x[d]^2 ; k>=384 -> x[d-384]
// B matrix [K=768][CPAD]:      k<384 -> w2[c][d]; k>=384 -> -2*w2[c][d]*ctr[c][d]
// afrag[((g*24 + kt)*4 + lg)*16 + row][e] ; bfrag[((nt*24 + kt)*4 + lg)*16 + col][e]

// ---------------- prep: bid<112 -> B-frags + a2 + present + init; else A-frags
__global__ __launch_bounds__(256) void k_prep(const float* __restrict__ inputs,
                                              const float* __restrict__ centers,
                                              const float* __restrict__ cw,
                                              const int* __restrict__ targets,
                                              ushort* __restrict__ bfrag,
                                              ushort* __restrict__ afrag,
                                              float* __restrict__ a2,
                                              int* __restrict__ present,
                                              int* __restrict__ apmax,
                                              int* __restrict__ anmin,
                                              int* __restrict__ cdminI) {
    int bid = blockIdx.x, t = threadIdx.x;

    if (bid < CPAD) {
        int c = bid;
        int nt = c >> 4, col = c & 15;
        __shared__ float sred[4];
        __shared__ int ps[4];

        float acc = 0.f;
        if (c < C_N) {
#pragma unroll
            for (int it = 0; it < 3; it++) {
                int k = t + it * 256;
                int d = (k < 384) ? k : k - 384;
                float wv = exp2f(cw[c * D_N + d]);
                float ce = centers[c * D_N + d];
                float val;
                if (k < 384) { val = wv; acc = fmaf(wv * ce, ce, acc); }
                else         { val = -2.f * wv * ce; }
                int kt = k >> 5, kr = k & 31, lg = kr >> 3, e = kr & 7;
                bfrag[(((nt * 24 + kt) * 4 + lg) * 16 + col) * 8 + e] = (ushort)f2bf(val);
            }
        } else {
#pragma unroll
            for (int it = 0; it < 3; it++) {
                int k = t + it * 256;
                int kt = k >> 5, kr = k & 31, lg = kr >> 3, e = kr & 7;
                bfrag[(((nt * 24 + kt) * 4 + lg) * 16 + col) * 8 + e] = 0;
            }
        }
        for (int m = 1; m < 64; m <<= 1) acc += __shfl_xor(acc, m, 64);

        int pr = 0;
        if (c < C_N)
            for (int i = t; i < B_N; i += 256) pr |= (targets[i] == c) ? 1 : 0;
        pr = __any(pr) ? 1 : 0;

        if ((t & 63) == 0) { sred[t >> 6] = acc; ps[t >> 6] = pr; }

        int idx = bid * 256 + t;               // 28672 covers 4096
        if (idx < B_N) {
            apmax[idx] = 0;                    // all g > 0
            anmin[idx] = 0x7F800000;           // +inf
        }
        if (bid == 0 && t < CPAD) cdminI[t] = 0x7F800000;

        __syncthreads();
        if (t == 0) {
            a2[c] = (c < C_N) ? ((sred[0] + sred[1]) + (sred[2] + sred[3])) : 0.f;
            present[c] = (c < C_N) ? (ps[0] | ps[1] | ps[2] | ps[3]) : 0;
        }
    } else {
        // ---- A-fragment build for row-group g (16 rows x K=768)
        int g = bid - CPAD;                    // 0..263
#pragma unroll
        for (int it = 0; it < 6; it++) {
            int cid = t + it * 256;            // 0..1535
            int row = cid & 15;
            int kc  = cid >> 4;                // 8-k chunk, 0..95
            const float* src;
            if (g < 256) {
                src = inputs + (size_t)(g * 16 + row) * D_N;
            } else {
                int cr = min((g - 256) * 16 + row, C_N - 1);
                src = centers + (size_t)cr * D_N;
            }
            int d0 = (kc < 48) ? kc * 8 : (kc - 48) * 8;
            float4 v0 = *(const float4*)(src + d0);
            float4 v1 = *(const float4*)(src + d0 + 4);
            short8 o;
            if (kc < 48) {
                o[0] = f2bf(v0.x * v0.x); o[1] = f2bf(v0.y * v0.y);
                o[2] = f2bf(v0.z * v0.z); o[3] = f2bf(v0.w * v0.w);
                o[4] = f2bf(v1.x * v1.x); o[5] = f2bf(v1.y * v1.y);
                o[6] = f2bf(v1.z * v1.z); o[7] = f2bf(v1.w * v1.w);
            } else {
                o[0] = f2bf(v0.x); o[1] = f2bf(v0.y);
                o[2] = f2bf(v0.z); o[3] = f2bf(v0.w);
                o[4] = f2bf(v1.x); o[5] = f2bf(v1.y);
                o[6] = f2bf(v1.z); o[7] = f2bf(v1.w);
            }
            int kt = kc >> 2, lg = kc & 3;
            *(short8*)(afrag + (size_t)(((g * 24 + kt) * 4 + lg) * 16 + row) * 8) = o;
        }
    }
}

// ---------------- main: fragment GEMM, 2-way K-split per output tile.
// block = 4 waves: wave w -> sub-group sg = w&1 (16 rows), K-half kh = w>>1.
// Waves kh=1 write acc to LDS; waves kh=0 add and run the epilogue.
__global__ __launch_bounds__(256) void k_main(const ushort* __restrict__ afrag,
                                              const ushort* __restrict__ bfrag,
                                              const int* __restrict__ targets,
                                              const float* __restrict__ a2g,
                                              const int* __restrict__ present,
                                              int* __restrict__ apmax,
                                              int* __restrict__ anmin,
                                              int* __restrict__ cdminI) {
    __shared__ __align__(16) f32x4 red[2][64];   // 2048 B

    int tid = threadIdx.x;
    int w   = tid >> 6;
    int l   = tid & 63;
    int nt  = blockIdx.x;
    int rt2 = blockIdx.y;
    int c0  = nt * 16;
    bool isc = (rt2 >= 128);

    int sg = w & 1;
    int kh = w >> 1;
    int g  = isc ? (256 + (rt2 - 128) * 2 + sg) : (rt2 * 2 + sg);
    int slot = (l >> 4) * 16 + (l & 15);

    const short8* A = (const short8*)afrag + (size_t)g * 24 * 64 + kh * 12 * 64;
    const short8* B = (const short8*)bfrag + (size_t)nt * 24 * 64 + kh * 12 * 64;

    f32x4 acc0 = {0.f, 0.f, 0.f, 0.f};
    f32x4 acc1 = {0.f, 0.f, 0.f, 0.f};
#pragma unroll 6
    for (int kt = 0; kt < 12; kt++) {
        short8 a = A[kt * 64 + slot];
        short8 b = B[kt * 64 + slot];
        if (kt & 1) acc1 = __builtin_amdgcn_mfma_f32_16x16x32_bf16(a, b, acc1, 0, 0, 0);
        else        acc0 = __builtin_amdgcn_mfma_f32_16x16x32_bf16(a, b, acc0, 0, 0, 0);
    }
    f32x4 acc = acc0 + acc1;

    // ---- combine K-halves: kh=1 publishes, kh=0 consumes
    if (kh == 1) red[sg][l] = acc;
    __syncthreads();
    if (kh == 1) return;
    acc = acc + red[sg][l];

    // ---- epilogue: D lane l = row (l>>4)*4 + r (within group's 16), col l&15
    int c = c0 + (l & 15);
    float a2v = a2g[c];
    int prs = present[c];

    if (!isc) {
#pragma unroll
        for (int r = 0; r < 4; r++) {
            float gv = sqrtf(fmaxf(a2v + acc[r], EPSF));
            int row = g * 16 + (l >> 4) * 4 + r;
            int ti  = targets[row];               // 16-lane broadcast read
            float ap = (c == ti) ? gv : -1.f;
            float an = (prs && c != ti) ? gv : INFINITY;
#pragma unroll
            for (int m = 1; m < 16; m <<= 1) {
                ap = fmaxf(ap, __shfl_xor(ap, m, 64));
                an = fminf(an, __shfl_xor(an, m, 64));
            }
            if ((l & 15) == 0) {
                if (ap > 0.f) atomicMax(&apmax[row], __float_as_int(ap));
                atomicMin(&anmin[row], __float_as_int(an));
            }
        }
    } else {
        float m = INFINITY;
#pragma unroll
        for (int r = 0; r < 4; r++) {
            float gv = sqrtf(fmaxf(a2v + acc[r], EPSF));
            int jg = (g - 256) * 16 + (l >> 4) * 4 + r;
            if (jg < C_N && jg != c) m = fminf(m, gv);
        }
        m = fminf(m, __shfl_xor(m, 16, 64));
        m = fminf(m, __shfl_xor(m, 32, 64));
        if (l < 16 && c < C_N && m < INFINITY)
            atomicMin(&cdminI[c], __float_as_int(m));
    }
}

// ---------------- final: per-row loss from apmax/anmin + cdminI, sum
__global__ __launch_bounds__(1024) void k_final(const int* __restrict__ apmax,
                                                const int* __restrict__ anmin,
                                                const int* __restrict__ cdminI,
                                                const int* __restrict__ targets,
                                                float* __restrict__ out) {
    int tid = threadIdx.x;
    __shared__ float cd_s[C_N];
    if (tid < C_N) cd_s[tid] = __int_as_float(cdminI[tid]);
    __syncthreads();

    float sum = 0.f;
    for (int row = tid; row < B_N; row += 1024) {
        float ap = __int_as_float(apmax[row]);
        float an = __int_as_float(anmin[row]);
        float cc = cd_s[targets[row]];
        sum += (an >= cc) ? ap : (ap - an + cc);
    }
    for (int m = 1; m < 64; m <<= 1) sum += __shfl_xor(sum, m, 64);
    __shared__ float sw[16];
    if ((tid & 63) == 0) sw[tid >> 6] = sum;
    __syncthreads();
    if (tid < 64) {
        float v = (tid < 16) ? sw[tid] : 0.f;
        for (int m = 1; m < 16; m <<= 1) v += __shfl_xor(v, m, 64);
        if (tid == 0) out[0] = v / (float)B_N;
    }
}

extern "C" void kernel_launch(void* const* d_in, const int* in_sizes, int n_in,
                              void* d_out, int out_size, void* d_ws, size_t ws_size,
                              hipStream_t stream) {
    const float* inputs  = (const float*)d_in[0];
    const float* centers = (const float*)d_in[1];
    const float* cw      = (const float*)d_in[2];
    const int*   targets = (const int*)d_in[3];
    (void)in_sizes; (void)n_in; (void)out_size; (void)ws_size;

    char* ws = (char*)d_ws;
    ushort* bfrag   = (ushort*)(ws + 0);        // 7*24*64*8*2   = 172032 B
    ushort* afrag   = (ushort*)(ws + 172032);   // 264*24*64*8*2 = 6488064 B
    int*    apmax   = (int*)  (ws + 6660096);   // 16384 B
    int*    anmin   = (int*)  (ws + 6676480);   // 16384 B
    float*  a2      = (float*)(ws + 6692864);   // 448 B
    int*    present = (int*)  (ws + 6693376);   // 448 B
    int*    cdminI  = (int*)  (ws + 6693888);   // 448 B

    k_prep<<<CPAD + NGRP, 256, 0, stream>>>(inputs, centers, cw, targets,
                                            bfrag, afrag, a2, present,
                                            apmax, anmin, cdminI);
    dim3 grid(NTILES, NRT2);   // 7 x 132 = 924 blocks
    k_main<<<grid, 256, 0, stream>>>(afrag, bfrag, targets, a2, present,
                                     apmax, anmin, cdminI);
    k_final<<<1, 1024, 0, stream>>>(apmax, anmin, cdminI, targets, (float*)d_out);
}

// Round 23
// 21.403 us; speedup vs baseline: 1.2526x; 1.2526x over previous
//
#include <hip/hip_runtime.h>
#include <math.h>

#define B_N 4096
#define C_N 100
#define CPAD 112
#define D_N 384
#define EPSF 1e-12f
#define NTILES 7          // class tiles of 16 (112 padded)
#define NKT24 24          // K=768 -> 24 ktiles of 32
#define NRT 64            // 64 input rowtiles (64 rows each); rt 64,65 = centers
#define NGRP 264          // 256 input row-groups of 16 + 8 center groups
#define GRID_MAIN 504     // 8 xcd-slots * 7 ntiles * 9 rowtile-groups (72 padded rt)

typedef __attribute__((ext_vector_type(8))) short short8;
typedef __attribute__((ext_vector_type(4))) float f32x4;

static __device__ __forceinline__ short f2bf(float f) {
    unsigned u = __float_as_uint(f);
    u = (u + 0x7FFFu + ((u >> 16) & 1u)) >> 16;
    return (short)u;
}

// Fragment layouts (HW-verified r20): lane l, elem e of a 16x16x32 frag holds
//   A[row = l&15][k = (l>>4)*8 + e]   /   B[k = (l>>4)*8 + e][col = l&15]
// A matrix [4224 rows][K=768]: k<384 -> x[d]^2 ; k>=384 -> x[d-384]
// B matrix [K=768][CPAD]:      k<384 -> w2[c][d]; k>=384 -> -2*w2[c][d]*ctr[c][d]
// afrag[((g*24 + kt)*4 + lg)*16 + row][e] ; bfrag[((nt*24 + kt)*4 + lg)*16 + col][e]

// ---------------- prep: bid<112 -> B-frags + a2 + present + init; else A-frags
__global__ __launch_bounds__(256) void k_prep(const float* __restrict__ inputs,
                                              const float* __restrict__ centers,
                                              const float* __restrict__ cw,
                                              const int* __restrict__ targets,
                                              ushort* __restrict__ bfrag,
                                              ushort* __restrict__ afrag,
                                              float* __restrict__ a2,
                                              int* __restrict__ present,
                                              int* __restrict__ apmax,
                                              int* __restrict__ anmin,
                                              int* __restrict__ cdminI) {
    int bid = blockIdx.x, t = threadIdx.x;

    if (bid < CPAD) {
        int c = bid;
        int nt = c >> 4, col = c & 15;
        __shared__ float sred[4];
        __shared__ int ps[4];

        float acc = 0.f;
        if (c < C_N) {
#pragma unroll
            for (int it = 0; it < 3; it++) {
                int k = t + it * 256;
                int d = (k < 384) ? k : k - 384;
                float wv = exp2f(cw[c * D_N + d]);
                float ce = centers[c * D_N + d];
                float val;
                if (k < 384) { val = wv; acc = fmaf(wv * ce, ce, acc); }
                else         { val = -2.f * wv * ce; }
                int kt = k >> 5, kr = k & 31, lg = kr >> 3, e = kr & 7;
                bfrag[(((nt * 24 + kt) * 4 + lg) * 16 + col) * 8 + e] = (ushort)f2bf(val);
            }
        } else {
#pragma unroll
            for (int it = 0; it < 3; it++) {
                int k = t + it * 256;
                int kt = k >> 5, kr = k & 31, lg = kr >> 3, e = kr & 7;
                bfrag[(((nt * 24 + kt) * 4 + lg) * 16 + col) * 8 + e] = 0;
            }
        }
        for (int m = 1; m < 64; m <<= 1) acc += __shfl_xor(acc, m, 64);

        int pr = 0;
        if (c < C_N)
            for (int i = t; i < B_N; i += 256) pr |= (targets[i] == c) ? 1 : 0;
        pr = __any(pr) ? 1 : 0;

        if ((t & 63) == 0) { sred[t >> 6] = acc; ps[t >> 6] = pr; }

        int idx = bid * 256 + t;               // 28672 covers 4096
        if (idx < B_N) {
            apmax[idx] = 0;                    // all g > 0
            anmin[idx] = 0x7F800000;           // +inf
        }
        if (bid == 0 && t < CPAD) cdminI[t] = 0x7F800000;

        __syncthreads();
        if (t == 0) {
            a2[c] = (c < C_N) ? ((sred[0] + sred[1]) + (sred[2] + sred[3])) : 0.f;
            present[c] = (c < C_N) ? (ps[0] | ps[1] | ps[2] | ps[3]) : 0;
        }
    } else {
        // ---- A-fragment build for row-group g (16 rows x K=768)
        int g = bid - CPAD;                    // 0..263
#pragma unroll
        for (int it = 0; it < 6; it++) {
            int cid = t + it * 256;            // 0..1535
            int row = cid & 15;
            int kc  = cid >> 4;                // 8-k chunk, 0..95
            const float* src;
            if (g < 256) {
                src = inputs + (size_t)(g * 16 + row) * D_N;
            } else {
                int cr = min((g - 256) * 16 + row, C_N - 1);
                src = centers + (size_t)cr * D_N;
            }
            int d0 = (kc < 48) ? kc * 8 : (kc - 48) * 8;
            float4 v0 = *(const float4*)(src + d0);
            float4 v1 = *(const float4*)(src + d0 + 4);
            short8 o;
            if (kc < 48) {
                o[0] = f2bf(v0.x * v0.x); o[1] = f2bf(v0.y * v0.y);
                o[2] = f2bf(v0.z * v0.z); o[3] = f2bf(v0.w * v0.w);
                o[4] = f2bf(v1.x * v1.x); o[5] = f2bf(v1.y * v1.y);
                o[6] = f2bf(v1.z * v1.z); o[7] = f2bf(v1.w * v1.w);
            } else {
                o[0] = f2bf(v0.x); o[1] = f2bf(v0.y);
                o[2] = f2bf(v0.z); o[3] = f2bf(v0.w);
                o[4] = f2bf(v1.x); o[5] = f2bf(v1.y);
                o[6] = f2bf(v1.z); o[7] = f2bf(v1.w);
            }
            int kt = kc >> 2, lg = kc & 3;
            *(short8*)(afrag + (size_t)(((g * 24 + kt) * 4 + lg) * 16 + row) * 8) = o;
        }
    }
}

// ---------------- main: pure fragment GEMM, no LDS, no barriers (r21 body).
// XCD-grouped decode: all 7 ntiles of a rowtile share b%8 -> same XCD under
// round-robin dispatch -> per-XCD A-footprint ~0.9 MB (L2-resident), no 7x dup.
__global__ __launch_bounds__(256) void k_main(const ushort* __restrict__ afrag,
                                              const ushort* __restrict__ bfrag,
                                              const int* __restrict__ targets,
                                              const float* __restrict__ a2g,
                                              const int* __restrict__ present,
                                              int* __restrict__ apmax,
                                              int* __restrict__ anmin,
                                              int* __restrict__ cdminI) {
    int b = blockIdx.x;
    int xs  = b & 7;          // xcd slot
    int q   = b >> 3;         // 0..62
    int nt  = q % 7;
    int rtg = q / 7;          // 0..8
    int rt  = xs + 8 * rtg;   // 0..71
    if (rt >= NRT + 2) return;   // uniform early-out, no barriers in kernel

    int tid = threadIdx.x;
    int w   = tid >> 6;
    int l   = tid & 63;
    int c0  = nt * 16;
    bool isc = (rt >= NRT);

    int g = isc ? (256 + (rt - NRT) * 4 + w) : (rt * 4 + w);
    int slot = (l >> 4) * 16 + (l & 15);

    const short8* A = (const short8*)afrag + (size_t)g * 24 * 64;
    const short8* B = (const short8*)bfrag + (size_t)nt * 24 * 64;

    f32x4 acc0 = {0.f, 0.f, 0.f, 0.f};
    f32x4 acc1 = {0.f, 0.f, 0.f, 0.f};
#pragma unroll 6
    for (int kt = 0; kt < NKT24; kt++) {
        short8 a = A[kt * 64 + slot];
        short8 bb = B[kt * 64 + slot];
        if (kt & 1) acc1 = __builtin_amdgcn_mfma_f32_16x16x32_bf16(a, bb, acc1, 0, 0, 0);
        else        acc0 = __builtin_amdgcn_mfma_f32_16x16x32_bf16(a, bb, acc0, 0, 0, 0);
    }
    f32x4 acc = acc0 + acc1;

    // ---- epilogue: D lane l = row (l>>4)*4 + r (within wave's 16), col l&15
    int c = c0 + (l & 15);
    float a2v = a2g[c];
    int prs = present[c];

    if (!isc) {
#pragma unroll
        for (int r = 0; r < 4; r++) {
            float gv = sqrtf(fmaxf(a2v + acc[r], EPSF));
            int rw  = w * 16 + (l >> 4) * 4 + r;
            int row = rt * 64 + rw;
            int ti  = targets[row];               // 16-lane broadcast read
            float ap = (c == ti) ? gv : -1.f;
            float an = (prs && c != ti) ? gv : INFINITY;
#pragma unroll
            for (int m = 1; m < 16; m <<= 1) {
                ap = fmaxf(ap, __shfl_xor(ap, m, 64));
                an = fminf(an, __shfl_xor(an, m, 64));
            }
            if ((l & 15) == 0) {
                if (ap > 0.f) atomicMax(&apmax[row], __float_as_int(ap));
                atomicMin(&anmin[row], __float_as_int(an));
            }
        }
    } else {
        float m = INFINITY;
#pragma unroll
        for (int r = 0; r < 4; r++) {
            float gv = sqrtf(fmaxf(a2v + acc[r], EPSF));
            int jg = (rt - NRT) * 64 + w * 16 + (l >> 4) * 4 + r;
            if (jg < C_N && jg != c) m = fminf(m, gv);
        }
        m = fminf(m, __shfl_xor(m, 16, 64));
        m = fminf(m, __shfl_xor(m, 32, 64));
        if (l < 16 && c < C_N && m < INFINITY)
            atomicMin(&cdminI[c], __float_as_int(m));
    }
}

// ---------------- final: per-row loss from apmax/anmin + cdminI, sum
__global__ __launch_bounds__(1024) void k_final(const int* __restrict__ apmax,
                                                const int* __restrict__ anmin,
                                                const int* __restrict__ cdminI,
                                                const int* __restrict__ targets,
                                                float* __restrict__ out) {
    int tid = threadIdx.x;
    __shared__ float cd_s[C_N];
    if (tid < C_N) cd_s[tid] = __int_as_float(cdminI[tid]);
    __syncthreads();

    float sum = 0.f;
    for (int row = tid; row < B_N; row += 1024) {
        float ap = __int_as_float(apmax[row]);
        float an = __int_as_float(anmin[row]);
        float cc = cd_s[targets[row]];
        sum += (an >= cc) ? ap : (ap - an + cc);
    }
    for (int m = 1; m < 64; m <<= 1) sum += __shfl_xor(sum, m, 64);
    __shared__ float sw[16];
    if ((tid & 63) == 0) sw[tid >> 6] = sum;
    __syncthreads();
    if (tid < 64) {
        float v = (tid < 16) ? sw[tid] : 0.f;
        for (int m = 1; m < 16; m <<= 1) v += __shfl_xor(v, m, 64);
        if (tid == 0) out[0] = v / (float)B_N;
    }
}

extern "C" void kernel_launch(void* const* d_in, const int* in_sizes, int n_in,
                              void* d_out, int out_size, void* d_ws, size_t ws_size,
                              hipStream_t stream) {
    const float* inputs  = (const float*)d_in[0];
    const float* centers = (const float*)d_in[1];
    const float* cw      = (const float*)d_in[2];
    const int*   targets = (const int*)d_in[3];
    (void)in_sizes; (void)n_in; (void)out_size; (void)ws_size;

    char* ws = (char*)d_ws;
    ushort* bfrag   = (ushort*)(ws + 0);        // 7*24*64*8*2   = 172032 B
    ushort* afrag   = (ushort*)(ws + 172032);   // 264*24*64*8*2 = 6488064 B
    int*    apmax   = (int*)  (ws + 6660096);   // 16384 B
    int*    anmin   = (int*)  (ws + 6676480);   // 16384 B
    float*  a2      = (float*)(ws + 6692864);   // 448 B
    int*    present = (int*)  (ws + 6693376);   // 448 B
    int*    cdminI  = (int*)  (ws + 6693888);   // 448 B

    k_prep<<<CPAD + NGRP, 256, 0, stream>>>(inputs, centers, cw, targets,
                                            bfrag, afrag, a2, present,
                                            apmax, anmin, cdminI);
    k_main<<<GRID_MAIN, 256, 0, stream>>>(afrag, bfrag, targets, a2, present,
                                          apmax, anmin, cdminI);
    k_final<<<1, 1024, 0, stream>>>(apmax, anmin, cdminI, targets, (float*)d_out);
}

// Round 24
// 19.375 us; speedup vs baseline: 1.3837x; 1.1047x over previous
//
#include <hip/hip_runtime.h>
#include <math.h>

#define B_N 4096
#define C_N 100
#define CPAD 112
#define D_N 384
#define EPSF 1e-12f
#define NTILES 7          // class tiles of 16 (112 padded)
#define NKT24 24          // K=768 -> 24 ktiles of 32
#define NRT 64            // 64 input rowtiles (64 rows each); rt 64,65 = centers
#define NAB 288           // A-build blocks: 8 xcd-slots * 36 (padded)
#define GRID_MAIN 504     // 8 xcd-slots * 7 ntiles * 9 rowtile-groups (72 padded rt)

typedef __attribute__((ext_vector_type(8))) short short8;
typedef __attribute__((ext_vector_type(4))) float f32x4;

static __device__ __forceinline__ short f2bf(float f) {
    unsigned u = __float_as_uint(f);
    u = (u + 0x7FFFu + ((u >> 16) & 1u)) >> 16;
    return (short)u;
}

// Fragment layouts (HW-verified r20): lane l, elem e of a 16x16x32 frag holds
//   A[row = l&15][k = (l>>4)*8 + e]   /   B[k = (l>>4)*8 + e][col = l&15]
// A matrix [4224 rows][K=768]: k<384 -> x[d]^2 ; k>=384 -> x[d-384]
// B matrix [K=768][CPAD]:      k<384 -> w2[c][d]; k>=384 -> -2*w2[c][d]*ctr[c][d]
// afrag[((g*24 + kt)*4 + lg)*16 + row][e] ; bfrag[((nt*24 + kt)*4 + lg)*16 + col][e]
//
// XCD alignment (r23 win, extended): k_main block b has b%8 = rt%8. k_prep A-build
// block for group g is placed at j%8 = (g/4)%8 = rt%8 -> afrag written and read in
// the SAME XCD's L2 (no L3 round-trip for the hand-off).

// ---------------- prep: bid<112 -> B-frags + a2 + present + init; else A-frags
__global__ __launch_bounds__(256) void k_prep(const float* __restrict__ inputs,
                                              const float* __restrict__ centers,
                                              const float* __restrict__ cw,
                                              const int* __restrict__ targets,
                                              ushort* __restrict__ bfrag,
                                              ushort* __restrict__ afrag,
                                              float* __restrict__ a2,
                                              int* __restrict__ present,
                                              int* __restrict__ apmax,
                                              int* __restrict__ anmin,
                                              int* __restrict__ cdminI) {
    int bid = blockIdx.x, t = threadIdx.x;

    if (bid < CPAD) {
        int c = bid;
        int nt = c >> 4, col = c & 15;
        __shared__ float sred[4];
        __shared__ int ps[4];

        float acc = 0.f;
        if (c < C_N) {
#pragma unroll
            for (int it = 0; it < 3; it++) {
                int k = t + it * 256;
                int d = (k < 384) ? k : k - 384;
                float wv = exp2f(cw[c * D_N + d]);
                float ce = centers[c * D_N + d];
                float val;
                if (k < 384) { val = wv; acc = fmaf(wv * ce, ce, acc); }
                else         { val = -2.f * wv * ce; }
                int kt = k >> 5, kr = k & 31, lg = kr >> 3, e = kr & 7;
                bfrag[(((nt * 24 + kt) * 4 + lg) * 16 + col) * 8 + e] = (ushort)f2bf(val);
            }
        } else {
#pragma unroll
            for (int it = 0; it < 3; it++) {
                int k = t + it * 256;
                int kt = k >> 5, kr = k & 31, lg = kr >> 3, e = kr & 7;
                bfrag[(((nt * 24 + kt) * 4 + lg) * 16 + col) * 8 + e] = 0;
            }
        }
        for (int m = 1; m < 64; m <<= 1) acc += __shfl_xor(acc, m, 64);

        int pr = 0;
        if (c < C_N)
            for (int i = t; i < B_N; i += 256) pr |= (targets[i] == c) ? 1 : 0;
        pr = __any(pr) ? 1 : 0;

        if ((t & 63) == 0) { sred[t >> 6] = acc; ps[t >> 6] = pr; }

        int idx = bid * 256 + t;               // 28672 covers 4096
        if (idx < B_N) {
            apmax[idx] = 0;                    // all g > 0
            anmin[idx] = 0x7F800000;           // +inf
        }
        if (bid == 0 && t < CPAD) cdminI[t] = 0x7F800000;

        __syncthreads();
        if (t == 0) {
            a2[c] = (c < C_N) ? ((sred[0] + sred[1]) + (sred[2] + sred[3])) : 0.f;
            present[c] = (c < C_N) ? (ps[0] | ps[1] | ps[2] | ps[3]) : 0;
        }
    } else {
        // ---- A-fragment build, XCD-aligned with the k_main reader.
        // j = bid-112 (112%8==0 so bid%8 == j%8). slot s = j%8, i = j/8 (0..35):
        // rt = s + 8*(i/4), w = i%4 -> group g; pad blocks (rt >= 66) exit.
        int j = bid - CPAD;
        int s = j & 7;
        int i = j >> 3;
        int rt = s + 8 * (i >> 2);
        int w  = i & 3;
        if (rt >= NRT + 2) return;
        int g = (rt < NRT) ? (rt * 4 + w) : (256 + (rt - NRT) * 4 + w);

#pragma unroll
        for (int it = 0; it < 6; it++) {
            int cid = t + it * 256;            // 0..1535
            int row = cid & 15;
            int kc  = cid >> 4;                // 8-k chunk, 0..95
            const float* src;
            if (g < 256) {
                src = inputs + (size_t)(g * 16 + row) * D_N;
            } else {
                int cr = min((g - 256) * 16 + row, C_N - 1);
                src = centers + (size_t)cr * D_N;
            }
            int d0 = (kc < 48) ? kc * 8 : (kc - 48) * 8;
            float4 v0 = *(const float4*)(src + d0);
            float4 v1 = *(const float4*)(src + d0 + 4);
            short8 o;
            if (kc < 48) {
                o[0] = f2bf(v0.x * v0.x); o[1] = f2bf(v0.y * v0.y);
                o[2] = f2bf(v0.z * v0.z); o[3] = f2bf(v0.w * v0.w);
                o[4] = f2bf(v1.x * v1.x); o[5] = f2bf(v1.y * v1.y);
                o[6] = f2bf(v1.z * v1.z); o[7] = f2bf(v1.w * v1.w);
            } else {
                o[0] = f2bf(v0.x); o[1] = f2bf(v0.y);
                o[2] = f2bf(v0.z); o[3] = f2bf(v0.w);
                o[4] = f2bf(v1.x); o[5] = f2bf(v1.y);
                o[6] = f2bf(v1.z); o[7] = f2bf(v1.w);
            }
            int kt = kc >> 2, lg = kc & 3;
            *(short8*)(afrag + (size_t)(((g * 24 + kt) * 4 + lg) * 16 + row) * 8) = o;
        }
    }
}

// ---------------- main: pure fragment GEMM, no LDS, no barriers (r23 body).
__global__ __launch_bounds__(256) void k_main(const ushort* __restrict__ afrag,
                                              const ushort* __restrict__ bfrag,
                                              const int* __restrict__ targets,
                                              const float* __restrict__ a2g,
                                              const int* __restrict__ present,
                                              int* __restrict__ apmax,
                                              int* __restrict__ anmin,
                                              int* __restrict__ cdminI) {
    int b = blockIdx.x;
    int xs  = b & 7;          // xcd slot
    int q   = b >> 3;         // 0..62
    int nt  = q % 7;
    int rtg = q / 7;          // 0..8
    int rt  = xs + 8 * rtg;   // 0..71
    if (rt >= NRT + 2) return;   // uniform early-out, no barriers in kernel

    int tid = threadIdx.x;
    int w   = tid >> 6;
    int l   = tid & 63;
    int c0  = nt * 16;
    bool isc = (rt >= NRT);

    int g = isc ? (256 + (rt - NRT) * 4 + w) : (rt * 4 + w);
    int slot = (l >> 4) * 16 + (l & 15);

    const short8* A = (const short8*)afrag + (size_t)g * 24 * 64;
    const short8* B = (const short8*)bfrag + (size_t)nt * 24 * 64;

    f32x4 acc0 = {0.f, 0.f, 0.f, 0.f};
    f32x4 acc1 = {0.f, 0.f, 0.f, 0.f};
#pragma unroll 6
    for (int kt = 0; kt < NKT24; kt++) {
        short8 a = A[kt * 64 + slot];
        short8 bb = B[kt * 64 + slot];
        if (kt & 1) acc1 = __builtin_amdgcn_mfma_f32_16x16x32_bf16(a, bb, acc1, 0, 0, 0);
        else        acc0 = __builtin_amdgcn_mfma_f32_16x16x32_bf16(a, bb, acc0, 0, 0, 0);
    }
    f32x4 acc = acc0 + acc1;

    // ---- epilogue: D lane l = row (l>>4)*4 + r (within wave's 16), col l&15
    int c = c0 + (l & 15);
    float a2v = a2g[c];
    int prs = present[c];

    if (!isc) {
#pragma unroll
        for (int r = 0; r < 4; r++) {
            float gv = sqrtf(fmaxf(a2v + acc[r], EPSF));
            int rw  = w * 16 + (l >> 4) * 4 + r;
            int row = rt * 64 + rw;
            int ti  = targets[row];               // 16-lane broadcast read
            float ap = (c == ti) ? gv : -1.f;
            float an = (prs && c != ti) ? gv : INFINITY;
#pragma unroll
            for (int m = 1; m < 16; m <<= 1) {
                ap = fmaxf(ap, __shfl_xor(ap, m, 64));
                an = fminf(an, __shfl_xor(an, m, 64));
            }
            if ((l & 15) == 0) {
                if (ap > 0.f) atomicMax(&apmax[row], __float_as_int(ap));
                atomicMin(&anmin[row], __float_as_int(an));
            }
        }
    } else {
        float m = INFINITY;
#pragma unroll
        for (int r = 0; r < 4; r++) {
            float gv = sqrtf(fmaxf(a2v + acc[r], EPSF));
            int jg = (rt - NRT) * 64 + w * 16 + (l >> 4) * 4 + r;
            if (jg < C_N && jg != c) m = fminf(m, gv);
        }
        m = fminf(m, __shfl_xor(m, 16, 64));
        m = fminf(m, __shfl_xor(m, 32, 64));
        if (l < 16 && c < C_N && m < INFINITY)
            atomicMin(&cdminI[c], __float_as_int(m));
    }
}

// ---------------- final: per-row loss from apmax/anmin + cdminI, sum
__global__ __launch_bounds__(1024) void k_final(const int* __restrict__ apmax,
                                                const int* __restrict__ anmin,
                                                const int* __restrict__ cdminI,
                                                const int* __restrict__ targets,
                                                float* __restrict__ out) {
    int tid = threadIdx.x;
    __shared__ float cd_s[C_N];
    if (tid < C_N) cd_s[tid] = __int_as_float(cdminI[tid]);
    __syncthreads();

    float sum = 0.f;
    for (int row = tid; row < B_N; row += 1024) {
        float ap = __int_as_float(apmax[row]);
        float an = __int_as_float(anmin[row]);
        float cc = cd_s[targets[row]];
        sum += (an >= cc) ? ap : (ap - an + cc);
    }
    for (int m = 1; m < 64; m <<= 1) sum += __shfl_xor(sum, m, 64);
    __shared__ float sw[16];
    if ((tid & 63) == 0) sw[tid >> 6] = sum;
    __syncthreads();
    if (tid < 64) {
        float v = (tid < 16) ? sw[tid] : 0.f;
        for (int m = 1; m < 16; m <<= 1) v += __shfl_xor(v, m, 64);
        if (tid == 0) out[0] = v / (float)B_N;
    }
}

extern "C" void kernel_launch(void* const* d_in, const int* in_sizes, int n_in,
                              void* d_out, int out_size, void* d_ws, size_t ws_size,
                              hipStream_t stream) {
    const float* inputs  = (const float*)d_in[0];
    const float* centers = (const float*)d_in[1];
    const float* cw      = (const float*)d_in[2];
    const int*   targets = (const int*)d_in[3];
    (void)in_sizes; (void)n_in; (void)out_size; (void)ws_size;

    char* ws = (char*)d_ws;
    ushort* bfrag   = (ushort*)(ws + 0);        // 7*24*64*8*2   = 172032 B
    ushort* afrag   = (ushort*)(ws + 172032);   // 264*24*64*8*2 = 6488064 B
    int*    apmax   = (int*)  (ws + 6660096);   // 16384 B
    int*    anmin   = (int*)  (ws + 6676480);   // 16384 B
    float*  a2      = (float*)(ws + 6692864);   // 448 B
    int*    present = (int*)  (ws + 6693376);   // 448 B
    int*    cdminI  = (int*)  (ws + 6693888);   // 448 B

    k_prep<<<CPAD + NAB, 256, 0, stream>>>(inputs, centers, cw, targets,
                                           bfrag, afrag, a2, present,
                                           apmax, anmin, cdminI);
    k_main<<<GRID_MAIN, 256, 0, stream>>>(afrag, bfrag, targets, a2, present,
                                          apmax, anmin, cdminI);
    k_final<<<1, 1024, 0, stream>>>(apmax, anmin, cdminI, targets, (float*)d_out);
}

// Round 25
// 19.344 us; speedup vs baseline: 1.3859x; 1.0016x over previous
//
#include <hip/hip_runtime.h>
#include <math.h>

#define B_N 4096
#define C_N 100
#define CPAD 112
#define D_N 384
#define EPSF 1e-12f
#define NTILES 7          // class tiles of 16 (112 padded)
#define NKT24 24          // K=768 -> 24 ktiles of 32
#define NRT 64            // 64 input rowtiles (64 rows each); rt 64,65 = centers
#define NAB 288           // A-build blocks: 8 xcd-slots * 36 (padded)
#define GRID_MAIN 504     // 8 xcd-slots * 7 ntiles * 9 rowtile-groups (72 padded rt)

typedef __attribute__((ext_vector_type(8))) short short8;
typedef __attribute__((ext_vector_type(4))) float f32x4;

static __device__ __forceinline__ short f2bf(float f) {
    unsigned u = __float_as_uint(f);
    u = (u + 0x7FFFu + ((u >> 16) & 1u)) >> 16;
    return (short)u;
}

// Fragment layouts (HW-verified r20): lane l, elem e of a 16x16x32 frag holds
//   A[row = l&15][k = (l>>4)*8 + e]   /   B[k = (l>>4)*8 + e][col = l&15]
// A matrix [4224 rows][K=768]: k<384 -> x[d]^2 ; k>=384 -> x[d-384]
// B matrix [K=768][CPAD]:      k<384 -> w2[c][d]; k>=384 -> -2*w2[c][d]*ctr[c][d]
// afrag[((g*24 + kt)*4 + lg)*16 + row][e] ; bfrag[((nt*24 + kt)*4 + lg)*16 + col][e]
// K-half pairing: dim d feeds ktile kt = d>>5 (x^2/w2 half) AND kt+12 (x/m2wc half)
// -> single read of the f32 source emits both fragments.
//
// XCD alignment (r23/r24 wins): k_main block b has b%8 = rt%8; k_prep A-build block
// for group g sits at j%8 = (g/4)%8 -> afrag written and read in the SAME XCD's L2.

// ---------------- prep: bid<112 -> B-frags + a2 + present + init; else A-frags
__global__ __launch_bounds__(256) void k_prep(const float* __restrict__ inputs,
                                              const float* __restrict__ centers,
                                              const float* __restrict__ cw,
                                              const int* __restrict__ targets,
                                              ushort* __restrict__ bfrag,
                                              ushort* __restrict__ afrag,
                                              float* __restrict__ a2,
                                              int* __restrict__ present,
                                              int* __restrict__ apmax,
                                              int* __restrict__ anmin,
                                              int* __restrict__ cdminI) {
    int bid = blockIdx.x, t = threadIdx.x;

    if (bid < CPAD) {
        int c = bid;
        int nt = c >> 4, col = c & 15;
        __shared__ float sred[4];
        __shared__ int ps[4];

        float acc = 0.f;
        if (c < C_N) {
            // one pass over d: emit w2 (ktile kt) and m2wc (ktile kt+12)
            for (int d = t; d < D_N; d += 256) {
                float wv = exp2f(cw[c * D_N + d]);
                float ce = centers[c * D_N + d];
                float p  = wv * ce;
                acc = fmaf(p, ce, acc);
                int kt = d >> 5, kr = d & 31, lg = kr >> 3, e = kr & 7;
                bfrag[(((nt * 24 + kt)      * 4 + lg) * 16 + col) * 8 + e] =
                    (ushort)f2bf(wv);
                bfrag[(((nt * 24 + kt + 12) * 4 + lg) * 16 + col) * 8 + e] =
                    (ushort)f2bf(-2.f * p);
            }
        } else {
            for (int d = t; d < D_N; d += 256) {
                int kt = d >> 5, kr = d & 31, lg = kr >> 3, e = kr & 7;
                bfrag[(((nt * 24 + kt)      * 4 + lg) * 16 + col) * 8 + e] = 0;
                bfrag[(((nt * 24 + kt + 12) * 4 + lg) * 16 + col) * 8 + e] = 0;
            }
        }
        for (int m = 1; m < 64; m <<= 1) acc += __shfl_xor(acc, m, 64);

        int pr = 0;
        if (c < C_N)
            for (int i = t; i < B_N; i += 256) pr |= (targets[i] == c) ? 1 : 0;
        pr = __any(pr) ? 1 : 0;

        if ((t & 63) == 0) { sred[t >> 6] = acc; ps[t >> 6] = pr; }

        int idx = bid * 256 + t;               // 28672 covers 4096
        if (idx < B_N) {
            apmax[idx] = 0;                    // all g > 0
            anmin[idx] = 0x7F800000;           // +inf
        }
        if (bid == 0 && t < CPAD) cdminI[t] = 0x7F800000;

        __syncthreads();
        if (t == 0) {
            a2[c] = (c < C_N) ? ((sred[0] + sred[1]) + (sred[2] + sred[3])) : 0.f;
            present[c] = (c < C_N) ? (ps[0] | ps[1] | ps[2] | ps[3]) : 0;
        }
    } else {
        // ---- A-fragment build, XCD-aligned with the k_main reader.
        // j = bid-112 (112%8==0). slot s = j%8, i = j/8 (0..35):
        // rt = s + 8*(i/4), w = i%4 -> group g; pad blocks (rt >= 66) exit.
        int j = bid - CPAD;
        int s = j & 7;
        int i = j >> 3;
        int rt = s + 8 * (i >> 2);
        int w  = i & 3;
        if (rt >= NRT + 2) return;
        int g = (rt < NRT) ? (rt * 4 + w) : (256 + (rt - NRT) * 4 + w);

        // 768 items: (row, 8-dim chunk kc in 0..47); each emits x^2-frag AND x-frag
#pragma unroll
        for (int it = 0; it < 3; it++) {
            int cid = t + it * 256;            // 0..767
            int row = cid & 15;
            int kc  = cid >> 4;                // 0..47
            const float* src;
            if (g < 256) {
                src = inputs + (size_t)(g * 16 + row) * D_N;
            } else {
                int cr = min((g - 256) * 16 + row, C_N - 1);
                src = centers + (size_t)cr * D_N;
            }
            float4 v0 = *(const float4*)(src + kc * 8);
            float4 v1 = *(const float4*)(src + kc * 8 + 4);
            short8 ox, ox2;
            ox[0] = f2bf(v0.x); ox[1] = f2bf(v0.y);
            ox[2] = f2bf(v0.z); ox[3] = f2bf(v0.w);
            ox[4] = f2bf(v1.x); ox[5] = f2bf(v1.y);
            ox[6] = f2bf(v1.z); ox[7] = f2bf(v1.w);
            ox2[0] = f2bf(v0.x * v0.x); ox2[1] = f2bf(v0.y * v0.y);
            ox2[2] = f2bf(v0.z * v0.z); ox2[3] = f2bf(v0.w * v0.w);
            ox2[4] = f2bf(v1.x * v1.x); ox2[5] = f2bf(v1.y * v1.y);
            ox2[6] = f2bf(v1.z * v1.z); ox2[7] = f2bf(v1.w * v1.w);
            int kt = kc >> 2, lg = kc & 3;
            *(short8*)(afrag + (size_t)(((g * 24 + kt)      * 4 + lg) * 16 + row) * 8) = ox2;
            *(short8*)(afrag + (size_t)(((g * 24 + kt + 12) * 4 + lg) * 16 + row) * 8) = ox;
        }
    }
}

// ---------------- main: pure fragment GEMM, no LDS, no barriers (r24 body).
__global__ __launch_bounds__(256) void k_main(const ushort* __restrict__ afrag,
                                              const ushort* __restrict__ bfrag,
                                              const int* __restrict__ targets,
                                              const float* __restrict__ a2g,
                                              const int* __restrict__ present,
                                              int* __restrict__ apmax,
                                              int* __restrict__ anmin,
                                              int* __restrict__ cdminI) {
    int b = blockIdx.x;
    int xs  = b & 7;          // xcd slot
    int q   = b >> 3;         // 0..62
    int nt  = q % 7;
    int rtg = q / 7;          // 0..8
    int rt  = xs + 8 * rtg;   // 0..71
    if (rt >= NRT + 2) return;   // uniform early-out, no barriers in kernel

    int tid = threadIdx.x;
    int w   = tid >> 6;
    int l   = tid & 63;
    int c0  = nt * 16;
    bool isc = (rt >= NRT);

    int g = isc ? (256 + (rt - NRT) * 4 + w) : (rt * 4 + w);
    int slot = (l >> 4) * 16 + (l & 15);

    const short8* A = (const short8*)afrag + (size_t)g * 24 * 64;
    const short8* B = (const short8*)bfrag + (size_t)nt * 24 * 64;

    f32x4 acc0 = {0.f, 0.f, 0.f, 0.f};
    f32x4 acc1 = {0.f, 0.f, 0.f, 0.f};
#pragma unroll 8
    for (int kt = 0; kt < NKT24; kt++) {
        short8 a = A[kt * 64 + slot];
        short8 bb = B[kt * 64 + slot];
        if (kt & 1) acc1 = __builtin_amdgcn_mfma_f32_16x16x32_bf16(a, bb, acc1, 0, 0, 0);
        else        acc0 = __builtin_amdgcn_mfma_f32_16x16x32_bf16(a, bb, acc0, 0, 0, 0);
    }
    f32x4 acc = acc0 + acc1;

    // ---- epilogue: D lane l = row (l>>4)*4 + r (within wave's 16), col l&15
    int c = c0 + (l & 15);
    float a2v = a2g[c];
    int prs = present[c];

    if (!isc) {
#pragma unroll
        for (int r = 0; r < 4; r++) {
            float gv = sqrtf(fmaxf(a2v + acc[r], EPSF));
            int rw  = w * 16 + (l >> 4) * 4 + r;
            int row = rt * 64 + rw;
            int ti  = targets[row];               // 16-lane broadcast read
            float ap = (c == ti) ? gv : -1.f;
            float an = (prs && c != ti) ? gv : INFINITY;
#pragma unroll
            for (int m = 1; m < 16; m <<= 1) {
                ap = fmaxf(ap, __shfl_xor(ap, m, 64));
                an = fminf(an, __shfl_xor(an, m, 64));
            }
            if ((l & 15) == 0) {
                if (ap > 0.f) atomicMax(&apmax[row], __float_as_int(ap));
                atomicMin(&anmin[row], __float_as_int(an));
            }
        }
    } else {
        float m = INFINITY;
#pragma unroll
        for (int r = 0; r < 4; r++) {
            float gv = sqrtf(fmaxf(a2v + acc[r], EPSF));
            int jg = (rt - NRT) * 64 + w * 16 + (l >> 4) * 4 + r;
            if (jg < C_N && jg != c) m = fminf(m, gv);
        }
        m = fminf(m, __shfl_xor(m, 16, 64));
        m = fminf(m, __shfl_xor(m, 32, 64));
        if (l < 16 && c < C_N && m < INFINITY)
            atomicMin(&cdminI[c], __float_as_int(m));
    }
}

// ---------------- final: per-row loss from apmax/anmin + cdminI, sum
__global__ __launch_bounds__(1024) void k_final(const int* __restrict__ apmax,
                                                const int* __restrict__ anmin,
                                                const int* __restrict__ cdminI,
                                                const int* __restrict__ targets,
                                                float* __restrict__ out) {
    int tid = threadIdx.x;
    __shared__ float cd_s[C_N];
    if (tid < C_N) cd_s[tid] = __int_as_float(cdminI[tid]);
    __syncthreads();

    float sum = 0.f;
    for (int row = tid; row < B_N; row += 1024) {
        float ap = __int_as_float(apmax[row]);
        float an = __int_as_float(anmin[row]);
        float cc = cd_s[targets[row]];
        sum += (an >= cc) ? ap : (ap - an + cc);
    }
    for (int m = 1; m < 64; m <<= 1) sum += __shfl_xor(sum, m, 64);
    __shared__ float sw[16];
    if ((tid & 63) == 0) sw[tid >> 6] = sum;
    __syncthreads();
    if (tid < 64) {
        float v = (tid < 16) ? sw[tid] : 0.f;
        for (int m = 1; m < 16; m <<= 1) v += __shfl_xor(v, m, 64);
        if (tid == 0) out[0] = v / (float)B_N;
    }
}

extern "C" void kernel_launch(void* const* d_in, const int* in_sizes, int n_in,
                              void* d_out, int out_size, void* d_ws, size_t ws_size,
                              hipStream_t stream) {
    const float* inputs  = (const float*)d_in[0];
    const float* centers = (const float*)d_in[1];
    const float* cw      = (const float*)d_in[2];
    const int*   targets = (const int*)d_in[3];
    (void)in_sizes; (void)n_in; (void)out_size; (void)ws_size;

    char* ws = (char*)d_ws;
    ushort* bfrag   = (ushort*)(ws + 0);        // 7*24*64*8*2   = 172032 B
    ushort* afrag   = (ushort*)(ws + 172032);   // 264*24*64*8*2 = 6488064 B
    int*    apmax   = (int*)  (ws + 6660096);   // 16384 B
    int*    anmin   = (int*)  (ws + 6676480);   // 16384 B
    float*  a2      = (float*)(ws + 6692864);   // 448 B
    int*    present = (int*)  (ws + 6693376);   // 448 B
    int*    cdminI  = (int*)  (ws + 6693888);   // 448 B

    k_prep<<<CPAD + NAB, 256, 0, stream>>>(inputs, centers, cw, targets,
                                           bfrag, afrag, a2, present,
                                           apmax, anmin, cdminI);
    k_main<<<GRID_MAIN, 256, 0, stream>>>(afrag, bfrag, targets, a2, present,
                                          apmax, anmin, cdminI);
    k_final<<<1, 1024, 0, stream>>>(apmax, anmin, cdminI, targets, (float*)d_out);
}